// Round 10
// baseline (124.923 us; speedup 1.0000x reference)
//
#include <hip/hip_runtime.h>

// DeepComplexRBF as 6 plain kernels in the captured graph (one per phase).
//   dist_sq[i] = sum_j |y[j] - G[i,j]|^2 ; phi[i] = exp(-dist_sq/(2 s[i]))
//   y_new[o]   = sum_i W[o,i]*phi[i] + b[o]
// 576 MB of G/W streamed once; ~280 MB L3-hit per replay (FETCH ~296 MB).
//
// r6 = 119.3 (no LDS, B=4)  r7 = 156.1 (VGPR strangled)  r8 = 118.2 (B=8,
// neutral -> ILP not the limiter). r9 theory: the per-lane global re-reads
// of the shared vector (y 32KB / phi 16KB) thrash L1 (same size as L1,
// evicted by the 128MB stream) and double VMEM-path traffic. Fix: stage
// the vector in LDS once per block (r1 idea) but KEEP r8's B=8 burst on
// the streaming operand; operand reads via ds_read_b128 (no vmcnt, no L1
// pollution). One variable changed vs r8: vector operand source.
// (Round 9 submission died to an unresponsive container; resubmitting.)

#define D0 1024
#define H  4096

__device__ __forceinline__ float wave_sum(float v) {
#pragma unroll
    for (int off = 32; off > 0; off >>= 1) v += __shfl_down(v, off, 64);
    return v;
}

// One wave per row: phi[row] = exp(-|y - G[row]|^2 / (2 s[row])).
// G is (2, ROWS, COLS); y is 2*COLS contiguous (re plane then im plane).
// Grid: ROWS/4 blocks x 256 threads. LDS: 2*COLS floats (8 or 32 KB).
template <int COLS, int ROWS>
__global__ __launch_bounds__(256, 4) void phi_k(
        const float* __restrict__ G, const float* __restrict__ y2,
        const float* __restrict__ sv, float* __restrict__ phi) {
    __shared__ float sy[2 * COLS];
    for (int j = threadIdx.x * 4; j < 2 * COLS; j += 1024)
        *(float4*)(sy + j) = *(const float4*)(y2 + j);
    __syncthreads();

    const int lane = threadIdx.x & 63;
    const int row = blockIdx.x * 4 + (threadIdx.x >> 6);
    const float* gre = G + (size_t)row * COLS;
    const float* gim = gre + (size_t)ROWS * COLS;

    constexpr int NIT = COLS / 256;            // float4 steps per lane (4|16)
    constexpr int B = (NIT < 8) ? NIT : 8;     // burst width (G stream only)

    float acc = 0.f;
#pragma unroll
    for (int pl = 0; pl < 2; ++pl) {           // 0: re plane, 1: im plane
        const float* gp = pl ? gim : gre;
        const float* yp = sy + pl * COLS;
#pragma unroll
        for (int it0 = 0; it0 < NIT; it0 += B) {
            float4 g[B];
#pragma unroll
            for (int u = 0; u < B; ++u)
                g[u] = *(const float4*)(gp + lane * 4 + (it0 + u) * 256);
#pragma unroll
            for (int u = 0; u < B; ++u) {
                const float4 yv = *(const float4*)(yp + lane * 4 + (it0 + u) * 256);
                float d;
                d = yv.x - g[u].x; acc += d * d;
                d = yv.y - g[u].y; acc += d * d;
                d = yv.z - g[u].z; acc += d * d;
                d = yv.w - g[u].w; acc += d * d;
            }
        }
    }
    acc = wave_sum(acc);
    if (lane == 0) phi[row] = expf(-acc / (2.0f * sv[row]));
}

// One wave per row: (ore,oim)[row] = W[row] . phi + b[row].
// W is (2, ROWS, COLS); bias is (2, ROWS) flat.
// Grid: ROWS/4 blocks x 256 threads. LDS: COLS floats (16 KB).
template <int COLS, int ROWS>
__global__ __launch_bounds__(256, 4) void w_k(
        const float* __restrict__ W, const float* __restrict__ bias,
        const float* __restrict__ phi,
        float* __restrict__ ore, float* __restrict__ oim) {
    __shared__ float sp[COLS];
    for (int j = threadIdx.x * 4; j < COLS; j += 1024)
        *(float4*)(sp + j) = *(const float4*)(phi + j);
    __syncthreads();

    const int lane = threadIdx.x & 63;
    const int row = blockIdx.x * 4 + (threadIdx.x >> 6);
    const float* wre = W + (size_t)row * COLS;
    const float* wim = wre + (size_t)ROWS * COLS;

    constexpr int NIT = COLS / 256;            // 16
    constexpr int B = (NIT < 8) ? NIT : 8;

    float ac[2] = {0.f, 0.f};
#pragma unroll
    for (int pl = 0; pl < 2; ++pl) {           // 0: re plane, 1: im plane
        const float* mp = pl ? wim : wre;
        float a = 0.f;
#pragma unroll
        for (int it0 = 0; it0 < NIT; it0 += B) {
            float4 m[B];
#pragma unroll
            for (int u = 0; u < B; ++u)
                m[u] = *(const float4*)(mp + lane * 4 + (it0 + u) * 256);
#pragma unroll
            for (int u = 0; u < B; ++u) {
                const float4 p = *(const float4*)(sp + lane * 4 + (it0 + u) * 256);
                a += m[u].x * p.x + m[u].y * p.y + m[u].z * p.z + m[u].w * p.w;
            }
        }
        ac[pl] = a;
    }
    const float ar = wave_sum(ac[0]);
    const float ai = wave_sum(ac[1]);
    if (lane == 0) {
        ore[row] = ar + bias[row];
        oim[row] = ai + bias[ROWS + row];
    }
}

extern "C" void kernel_launch(void* const* d_in, const int* in_sizes, int n_in,
                              void* d_out, int out_size, void* d_ws, size_t ws_size,
                              hipStream_t stream) {
    const float* x  = (const float*)d_in[0];
    const float* W1 = (const float*)d_in[1];
    const float* b1 = (const float*)d_in[2];
    const float* G1 = (const float*)d_in[3];
    const float* s1 = (const float*)d_in[4];
    const float* W2 = (const float*)d_in[5];
    const float* b2 = (const float*)d_in[6];
    const float* G2 = (const float*)d_in[7];
    const float* s2 = (const float*)d_in[8];
    const float* W3 = (const float*)d_in[9];
    const float* b3 = (const float*)d_in[10];
    const float* G3 = (const float*)d_in[11];
    const float* s3 = (const float*)d_in[12];
    float* out = (float*)d_out;   // (2, 1024)

    float* ws  = (float*)d_ws;
    float* phi = ws;              // 4096
    float* y2  = ws + H;          // 8192: y re plane then im plane (contig)
    // no init needed: phi/y fully written before first read each call

    // Layer 1 (x is (2, D0) contiguous = re plane then im plane)
    phi_k<D0, H><<<H / 4, 256, 0, stream>>>(G1, x, s1, phi);
    w_k<H, H><<<H / 4, 256, 0, stream>>>(W1, b1, phi, y2, y2 + H);
    // Layer 2
    phi_k<H, H><<<H / 4, 256, 0, stream>>>(G2, y2, s2, phi);
    w_k<H, H><<<H / 4, 256, 0, stream>>>(W2, b2, phi, y2, y2 + H);
    // Layer 3
    phi_k<H, H><<<H / 4, 256, 0, stream>>>(G3, y2, s3, phi);
    w_k<H, D0><<<D0 / 4, 256, 0, stream>>>(W3, b3, phi, out, out + D0);
}

// Round 11
// 112.138 us; speedup vs baseline: 1.1140x; 1.1140x over previous
//
#include <hip/hip_runtime.h>

// DeepComplexRBF as 6 plain kernels in the captured graph (one per phase).
//   dist_sq[i] = sum_j |y[j] - G[i,j]|^2 ; phi[i] = exp(-dist_sq/(2 s[i]))
//   y_new[o]   = sum_i W[o,i]*phi[i] + b[o]
// 576 MB of G/W streamed once; ~280 MB L3-hit per replay (FETCH ~296 MB).
//
// r6=119.3 (wave-per-row, B=4)  r7=156.1 (VGPR strangled)  r8=118.2 (B=8,
// neutral: ILP not limiter)  r10=124.9 (LDS staging: extra traffic, regress).
// r11 theory: r6/r8 have exactly 1 task per resident wave (4096 rows on
// 4096 waves, zero refill) -> kernel duration = slowest wave; ~50% L3-hit
// luck gives ~10-15% tail tax. Fix: block-per-row (4 waves x quarter-row,
// LDS combine), 4096 blocks vs 1024 resident -> ~4 tasks/slot dynamic
// refill averages memory luck. Bursts (B=4/quarter/plane) and per-lane
// global vector reads kept from r8.

#define D0 1024
#define H  4096

__device__ __forceinline__ float wave_sum(float v) {
#pragma unroll
    for (int off = 32; off > 0; off >>= 1) v += __shfl_down(v, off, 64);
    return v;
}

// Block-per-row: phi[row] = exp(-|y - G[row]|^2 / (2 s[row])).
// G is (2, ROWS, COLS); y2 is 2*COLS contiguous (re plane, im plane).
// Grid: ROWS blocks x 256 threads; wave w owns quarter w of the row.
template <int COLS, int ROWS>
__global__ __launch_bounds__(256, 4) void phi_bpr(
        const float* __restrict__ G, const float* __restrict__ y2,
        const float* __restrict__ sv, float* __restrict__ phi) {
    const int lane = threadIdx.x & 63;
    const int w = threadIdx.x >> 6;
    const int row = blockIdx.x;
    constexpr int QL = COLS / 4;               // floats per wave per plane
    constexpr int NIT = QL / 256;              // float4 steps (1|4)
    constexpr int B = (NIT < 8) ? NIT : 8;

    const float* gre = G + (size_t)row * COLS + w * QL;
    const float* gim = gre + (size_t)ROWS * COLS;

    float acc = 0.f;
#pragma unroll
    for (int pl = 0; pl < 2; ++pl) {           // 0: re plane, 1: im plane
        const float* gp = pl ? gim : gre;
        const float* yp = y2 + pl * COLS + w * QL;
#pragma unroll
        for (int it0 = 0; it0 < NIT; it0 += B) {
            float4 g[B], y[B];
#pragma unroll
            for (int u = 0; u < B; ++u) {
                const int j = lane * 4 + (it0 + u) * 256;
                g[u] = *(const float4*)(gp + j);
                y[u] = *(const float4*)(yp + j);
            }
#pragma unroll
            for (int u = 0; u < B; ++u) {
                float d;
                d = y[u].x - g[u].x; acc += d * d;
                d = y[u].y - g[u].y; acc += d * d;
                d = y[u].z - g[u].z; acc += d * d;
                d = y[u].w - g[u].w; acc += d * d;
            }
        }
    }
    acc = wave_sum(acc);
    __shared__ float sred[4];
    if (lane == 0) sred[w] = acc;
    __syncthreads();
    if (threadIdx.x == 0) {
        const float d = (sred[0] + sred[1]) + (sred[2] + sred[3]);
        phi[row] = expf(-d / (2.0f * sv[row]));
    }
}

// Block-per-row: (ore,oim)[row] = W[row] . phi + b[row].
// W is (2, ROWS, COLS); bias is (2, ROWS) flat.
// Grid: ROWS blocks x 256 threads; wave w owns quarter w of the row.
template <int COLS, int ROWS>
__global__ __launch_bounds__(256, 4) void w_bpr(
        const float* __restrict__ W, const float* __restrict__ bias,
        const float* __restrict__ phi,
        float* __restrict__ ore, float* __restrict__ oim) {
    const int lane = threadIdx.x & 63;
    const int w = threadIdx.x >> 6;
    const int row = blockIdx.x;
    constexpr int QL = COLS / 4;
    constexpr int NIT = QL / 256;              // 4
    constexpr int B = (NIT < 8) ? NIT : 8;

    const float* wre = W + (size_t)row * COLS + w * QL;
    const float* wim = wre + (size_t)ROWS * COLS;
    const float* ph0 = phi + w * QL;

    float ac[2] = {0.f, 0.f};
#pragma unroll
    for (int pl = 0; pl < 2; ++pl) {           // 0: re plane, 1: im plane
        const float* mp = pl ? wim : wre;
        float a = 0.f;
#pragma unroll
        for (int it0 = 0; it0 < NIT; it0 += B) {
            float4 m[B], p[B];
#pragma unroll
            for (int u = 0; u < B; ++u) {
                const int j = lane * 4 + (it0 + u) * 256;
                m[u] = *(const float4*)(mp + j);
                p[u] = *(const float4*)(ph0 + j);
            }
#pragma unroll
            for (int u = 0; u < B; ++u)
                a += m[u].x * p[u].x + m[u].y * p[u].y
                   + m[u].z * p[u].z + m[u].w * p[u].w;
        }
        ac[pl] = a;
    }
    const float ar = wave_sum(ac[0]);
    const float ai = wave_sum(ac[1]);
    __shared__ float sred[8];
    if (lane == 0) { sred[w] = ar; sred[4 + w] = ai; }
    __syncthreads();
    if (threadIdx.x == 0) {
        ore[row] = (sred[0] + sred[1]) + (sred[2] + sred[3]) + bias[row];
        oim[row] = (sred[4] + sred[5]) + (sred[6] + sred[7]) + bias[ROWS + row];
    }
}

extern "C" void kernel_launch(void* const* d_in, const int* in_sizes, int n_in,
                              void* d_out, int out_size, void* d_ws, size_t ws_size,
                              hipStream_t stream) {
    const float* x  = (const float*)d_in[0];
    const float* W1 = (const float*)d_in[1];
    const float* b1 = (const float*)d_in[2];
    const float* G1 = (const float*)d_in[3];
    const float* s1 = (const float*)d_in[4];
    const float* W2 = (const float*)d_in[5];
    const float* b2 = (const float*)d_in[6];
    const float* G2 = (const float*)d_in[7];
    const float* s2 = (const float*)d_in[8];
    const float* W3 = (const float*)d_in[9];
    const float* b3 = (const float*)d_in[10];
    const float* G3 = (const float*)d_in[11];
    const float* s3 = (const float*)d_in[12];
    float* out = (float*)d_out;   // (2, 1024)

    float* ws  = (float*)d_ws;
    float* phi = ws;              // 4096
    float* y2  = ws + H;          // 8192: y re plane then im plane (contig)
    // no init needed: phi/y fully written before first read each call

    // Layer 1 (x is (2, D0) contiguous = re plane then im plane)
    phi_bpr<D0, H><<<H, 256, 0, stream>>>(G1, x, s1, phi);
    w_bpr<H, H><<<H, 256, 0, stream>>>(W1, b1, phi, y2, y2 + H);
    // Layer 2
    phi_bpr<H, H><<<H, 256, 0, stream>>>(G2, y2, s2, phi);
    w_bpr<H, H><<<H, 256, 0, stream>>>(W2, b2, phi, y2, y2 + H);
    // Layer 3
    phi_bpr<H, H><<<H, 256, 0, stream>>>(G3, y2, s3, phi);
    w_bpr<H, D0><<<D0, 256, 0, stream>>>(W3, b3, phi, out, out + D0);
}